// Round 2
// baseline (398.783 us; speedup 1.0000x reference)
//
#include <hip/hip_runtime.h>
#include <cstdint>
#include <cstddef>

// ============================================================================
// ResMLP fused kernel for MI355X (gfx950) — round 10
//
// Round-9 structure (register-resident activations, 32x32x16 MFMA,
// weight-k-order permuted in prep, linear 1KB frag-blocks in LDS, zero bank
// conflicts) + the T3/T4 pipeline fix:
//  - TRIPLE-buffered 25.6KB half-panels (76.8KB LDS, 2 blocks/CU).
//  - Raw s_barrier + counted s_waitcnt vmcnt(12): the weights consumed in
//    phase u were staged in phase u-2; loads stay in flight ACROSS barriers
//    (never drain to vmcnt(0) in the main loop). Removes the per-phase
//    25.6KB L2-drain stall that left every pipe at ~25% in round 9.
//  - Phase order: barrier | issue stage(u+2) | boundary VALU (resid/relu)
//    | s_waitcnt vmcnt(12) | ds_read+MFMA.  Buffer-overwrite hazard is
//    fenced by the phase-start barrier (unit u+3 writes buf[u%3] only
//    after the barrier that ends phase u).
//  - s_setprio(1) around MFMA clusters (T5); first-kt MFMA takes a zero C
//    operand so the 80-op per-layer acc-zero loop disappears.
// ============================================================================

typedef __attribute__((ext_vector_type(8))) short bfrag8;     // 8 x bf16
typedef __attribute__((ext_vector_type(16))) float f32x16;    // MFMA 32x32 acc
typedef __attribute__((ext_vector_type(4))) uint32_t u32x4;

#define MFMA32(a, b, c) __builtin_amdgcn_mfma_f32_32x32x16_bf16((a), (b), (c), 0, 0, 0)

#define NFRAG_TOTAL 1855   // 245 embed + 32*50 layer + 10 head 1KB frag-blocks
#define HALF_BYTES  25600  // one stage unit (25 frag-blocks; embed tail 20, head 5)
#define HALF_ELEMS  12800

#define WAITVM(N) asm volatile("s_waitcnt vmcnt(" #N ")" ::: "memory")

static __device__ __forceinline__ uint16_t f2bf16u(float v) {
    uint32_t u = __builtin_bit_cast(uint32_t, v);
    uint32_t r = u + 0x7FFFu + ((u >> 16) & 1u);
    return (uint16_t)(r >> 16);
}
static __device__ __forceinline__ uint32_t pack2_bf16(float lo, float hi) {
    return (uint32_t)f2bf16u(lo) | ((uint32_t)f2bf16u(hi) << 16);
}
static __device__ __forceinline__ uint32_t cvtpk(float lo, float hi) {
    uint32_t r;
    asm("v_cvt_pk_bf16_f32 %0, %1, %2" : "=v"(r) : "v"(lo), "v"(hi));
    return r;
}
// async global->LDS, 16B per lane; lds dest = wave-uniform base + lane*16
static __device__ __forceinline__ void gl_lds16(const void* g, void* l) {
    __builtin_amdgcn_global_load_lds(
        (const __attribute__((address_space(1))) uint32_t*)g,
        (__attribute__((address_space(3))) uint32_t*)l, 16, 0, 0);
}

// ---------------------------------------------------------------------------
// prep: build 1KB A-fragment blocks (W^T as MFMA A operand, bf16).
// Block fb, lane l (h=l>>5, m32=l&31), elem j (byte 2j of lane's 16B):
//   embed  (fb<245):   kt=fb/5, mt=fb%5,  k natural = kt*16 + h*8 + j
//   layer  (fb<1845):  k permuted: khid = 32*(kt>>1)+16*(kt&1)+4h+(j&3)+8*(j>>2)
//   head   (else):     same permuted k; m>=10 zero-padded
// ---------------------------------------------------------------------------
__global__ __launch_bounds__(256) void resmlp_prep(
    const float* __restrict__ embed_w, const float* __restrict__ layer_w,
    const float* __restrict__ head_w, uint16_t* __restrict__ ws)
{
    const int fb = blockIdx.x * 4 + (threadIdx.x >> 6);
    if (fb >= NFRAG_TOTAL) return;
    const int l = threadIdx.x & 63;
    const int h = l >> 5, m32 = l & 31;
    float v[8];
    if (fb < 245) {
        const int kt = fb / 5, mt = fb % 5;
        const int m = mt * 32 + m32;
        const int kb = kt * 16 + h * 8;
#pragma unroll
        for (int j = 0; j < 8; ++j)
            v[j] = embed_w[(size_t)(kb + j) * 160 + m];
    } else if (fb < 1845) {
        const int t = fb - 245, L = t / 50, r = t % 50, kt = r / 5, mt = r % 5;
        const int m = mt * 32 + m32;
        const float* W = layer_w + (size_t)L * 25600;
        const int kb = 32 * (kt >> 1) + 16 * (kt & 1) + 4 * h;
#pragma unroll
        for (int j = 0; j < 8; ++j)
            v[j] = W[(size_t)(kb + (j & 3) + 8 * (j >> 2)) * 160 + m];
    } else {
        const int kt = fb - 1845;
        const int kb = 32 * (kt >> 1) + 16 * (kt & 1) + 4 * h;
#pragma unroll
        for (int j = 0; j < 8; ++j)
            v[j] = (m32 < 10) ? head_w[(kb + (j & 3) + 8 * (j >> 2)) * 10 + m32] : 0.f;
    }
    u32x4 wv;
    wv.x = pack2_bf16(v[0], v[1]);
    wv.y = pack2_bf16(v[2], v[3]);
    wv.z = pack2_bf16(v[4], v[5]);
    wv.w = pack2_bf16(v[6], v[7]);
    *(u32x4*)((char*)ws + (size_t)fb * 1024 + l * 16) = wv;
}

// ---------------------------------------------------------------------------
// compute helpers (local kt 0..4 within a half-panel buffer)
// ---------------------------------------------------------------------------
template<int NK>
static __device__ __forceinline__ void embed_loadx(const float* __restrict__ xb,
                                                   float4 (&xv)[10])
{
#pragma unroll
    for (int kt = 0; kt < NK; ++kt) {
        xv[2 * kt]     = *(const float4*)(xb + kt * 16);
        xv[2 * kt + 1] = *(const float4*)(xb + kt * 16 + 4);
    }
}

template<int NK>
static __device__ __forceinline__ void embed_mfma_h(
    const uint16_t* __restrict__ buf, const float4 (&xv)[10],
    f32x16 (&acc)[5], int lane8)
{
    __builtin_amdgcn_s_setprio(1);
#pragma unroll
    for (int kt = 0; kt < NK; ++kt) {
        const float4 v0 = xv[2 * kt], v1 = xv[2 * kt + 1];
        u32x4 bw;
        bw.x = cvtpk(v0.x, v0.y);
        bw.y = cvtpk(v0.z, v0.w);
        bw.z = cvtpk(v1.x, v1.y);
        bw.w = cvtpk(v1.z, v1.w);
        const bfrag8 b = __builtin_bit_cast(bfrag8, bw);
#pragma unroll
        for (int mt = 0; mt < 5; ++mt) {
            const bfrag8 a = *(const bfrag8*)(buf + (kt * 5 + mt) * 512 + lane8);
            acc[mt] = MFMA32(a, b, acc[mt]);
        }
    }
    __builtin_amdgcn_s_setprio(0);
}

// ZC: first kt uses a zero C operand (defines acc without a pre-zero pass)
template<int KT0, int NMT, bool ZC>
static __device__ __forceinline__ void layer_mfma_h(
    const uint16_t* __restrict__ buf, f32x16 (&acc)[5],
    const f32x16 (&resid)[5], int lane8)
{
    __builtin_amdgcn_s_setprio(1);
#pragma unroll
    for (int i = 0; i < 5; ++i) {
        const int kt = KT0 + i, ms = kt >> 1, rb = (kt & 1) * 8;
        u32x4 bw;
        bw.x = cvtpk(resid[ms][rb + 0], resid[ms][rb + 1]);
        bw.y = cvtpk(resid[ms][rb + 2], resid[ms][rb + 3]);
        bw.z = cvtpk(resid[ms][rb + 4], resid[ms][rb + 5]);
        bw.w = cvtpk(resid[ms][rb + 6], resid[ms][rb + 7]);
        const bfrag8 b = __builtin_bit_cast(bfrag8, bw);
#pragma unroll
        for (int mt = 0; mt < NMT; ++mt) {
            const bfrag8 a = *(const bfrag8*)(buf + (i * NMT + mt) * 512 + lane8);
            if (ZC && i == 0) {
                f32x16 z;
#pragma unroll
                for (int r = 0; r < 16; ++r) z[r] = 0.f;
                acc[mt] = MFMA32(a, b, z);
            } else {
                acc[mt] = MFMA32(a, b, acc[mt]);
            }
        }
    }
    __builtin_amdgcn_s_setprio(0);
}

// ---------------------------------------------------------------------------
__global__ __launch_bounds__(256, 2) void resmlp_main(
    const float* __restrict__ x,
    const float* __restrict__ embed_b,
    const float* __restrict__ head_b,
    const uint16_t* __restrict__ ws,
    float* __restrict__ out)
{
    extern __shared__ __align__(16) uint16_t lds[];   // 3 x 25600 B
    const int tid  = threadIdx.x;
    const int wave = tid >> 6, lane = tid & 63;
    const int hi = lane >> 5;
    const int lane8 = lane * 8;                       // u16 elems = lane*16 B
    const int batch = blockIdx.x * 128 + wave * 32 + (lane & 31);

    f32x16 acc[5], resid[5];
#pragma unroll
    for (int mt = 0; mt < 5; ++mt)
#pragma unroll
        for (int r = 0; r < 16; ++r) acc[mt][r] = 0.f;

    // stage unit u (76 units: 10 embed halves [u=9 has 20 blocks],
    // 64 layer halves, 2 head halves [5 blocks]) into buf[u%3]
    auto do_stage = [&](int u) {
        int S, C;
        if (u < 10)      { S = (u >> 1) * 50 + (u & 1) * 25; C = (u == 9) ? 20 : 25; }
        else if (u < 74) { S = 245 + (u - 10) * 25;          C = 25; }
        else             { S = 1845 + (u - 74) * 5;          C = 5; }
        const char* src = (const char*)ws + (size_t)S * 1024 + lane * 16;
        char* dst = (char*)lds + (u % 3) * HALF_BYTES + lane * 16;
        for (int i = wave; i < C; i += 4)
            gl_lds16(src + (size_t)i * 1024, dst + i * 1024);
    };

    // ---- prologue: 2 units in flight ----
    do_stage(0);
    do_stage(1);

    const float* xrow = x + (size_t)batch * 784 + hi * 8;

    // ---- embed: 5 chunks x 2 half-phases ----
    for (int c = 0; c < 5; ++c) {
        float4 xv[10];
        // phase A (u = 2c)
        __builtin_amdgcn_s_barrier();
        embed_loadx<5>(xrow + c * 160, xv);
        do_stage(2 * c + 2);
        WAITVM(11);
        embed_mfma_h<5>(lds + ((2 * c) % 3) * HALF_ELEMS, xv, acc, lane8);
        // phase B (u = 2c+1)
        __builtin_amdgcn_s_barrier();
        if (c < 4) embed_loadx<5>(xrow + c * 160 + 80, xv);
        else       embed_loadx<4>(xrow + c * 160 + 80, xv);
        do_stage(2 * c + 3);
        WAITVM(11);
        if (c < 4) embed_mfma_h<5>(lds + ((2 * c + 1) % 3) * HALF_ELEMS, xv, acc, lane8);
        else       embed_mfma_h<4>(lds + ((2 * c + 1) % 3) * HALF_ELEMS, xv, acc, lane8);
    }

    // ---- residual layers 0..30 (uniform pipeline, vmcnt(12)) ----
    for (int L = 0; L < 31; ++L) {
        const int u = 10 + 2 * L;
        const int bA = u % 3, bB = (u + 1) % 3;
        // phase A
        __builtin_amdgcn_s_barrier();
        do_stage(u + 2);
        if (L == 0) {
#pragma unroll
            for (int mt = 0; mt < 5; ++mt)
#pragma unroll
                for (int q2 = 0; q2 < 4; ++q2) {
                    const float4 b4 = *(const float4*)(embed_b + mt * 32 + q2 * 8 + hi * 4);
                    resid[mt][q2 * 4 + 0] = acc[mt][q2 * 4 + 0] + b4.x;
                    resid[mt][q2 * 4 + 1] = acc[mt][q2 * 4 + 1] + b4.y;
                    resid[mt][q2 * 4 + 2] = acc[mt][q2 * 4 + 2] + b4.z;
                    resid[mt][q2 * 4 + 3] = acc[mt][q2 * 4 + 3] + b4.w;
                }
        } else {
#pragma unroll
            for (int mt = 0; mt < 5; ++mt)
#pragma unroll
                for (int r = 0; r < 16; ++r)
                    resid[mt][r] += fmaxf(acc[mt][r], 0.f);
        }
        WAITVM(12);
        layer_mfma_h<0, 5, true>(lds + bA * HALF_ELEMS, acc, resid, lane8);
        // phase B
        __builtin_amdgcn_s_barrier();
        do_stage(u + 3);
        WAITVM(12);
        layer_mfma_h<5, 5, false>(lds + bB * HALF_ELEMS, acc, resid, lane8);
    }

    // ---- layer 31 (u=72,73): head units (5 blocks) enter the pipe ----
    {
        __builtin_amdgcn_s_barrier();
        do_stage(74);
#pragma unroll
        for (int mt = 0; mt < 5; ++mt)
#pragma unroll
            for (int r = 0; r < 16; ++r)
                resid[mt][r] += fmaxf(acc[mt][r], 0.f);
        WAITVM(7);                       // min own(u73)+own(u74) = 6+1
        layer_mfma_h<0, 5, true>(lds + 0 * HALF_ELEMS, acc, resid, lane8);   // 72%3=0
        __builtin_amdgcn_s_barrier();
        do_stage(75);
        WAITVM(2);                       // min own(u74)+own(u75) = 1+1
        layer_mfma_h<5, 5, false>(lds + 1 * HALF_ELEMS, acc, resid, lane8);  // 73%3=1
    }

    // ---- head (u=74,75): 10 kt, 1 m-tile ----
    {
        __builtin_amdgcn_s_barrier();
#pragma unroll
        for (int mt = 0; mt < 5; ++mt)
#pragma unroll
            for (int r = 0; r < 16; ++r)
                resid[mt][r] += fmaxf(acc[mt][r], 0.f);
        WAITVM(1);                       // min own(u75) = 1
        layer_mfma_h<0, 1, true>(lds + 2 * HALF_ELEMS, acc, resid, lane8);   // 74%3=2
        __builtin_amdgcn_s_barrier();
        WAITVM(0);                       // final drain (<=2 loads)
        layer_mfma_h<5, 1, false>(lds + 0 * HALF_ELEMS, acc, resid, lane8);  // 75%3=0
    }

    // epilogue: D row h' = (r&3)+8*(r>>2)+4*hi -> class index (h'<10)
    float* op = out + (size_t)batch * 10;
    if (hi == 0) {
        op[0] = acc[0][0] + head_b[0];
        op[1] = acc[0][1] + head_b[1];
        op[2] = acc[0][2] + head_b[2];
        op[3] = acc[0][3] + head_b[3];
        op[8] = acc[0][4] + head_b[8];
        op[9] = acc[0][5] + head_b[9];
    } else {
        op[4] = acc[0][0] + head_b[4];
        op[5] = acc[0][1] + head_b[5];
        op[6] = acc[0][2] + head_b[6];
        op[7] = acc[0][3] + head_b[7];
    }
}

// ---------------------------------------------------------------------------
extern "C" void kernel_launch(void* const* d_in, const int* in_sizes, int n_in,
                              void* d_out, int out_size, void* d_ws, size_t ws_size,
                              hipStream_t stream) {
    (void)in_sizes; (void)n_in; (void)out_size; (void)ws_size;
    const float* x       = (const float*)d_in[0];
    const float* embed_w = (const float*)d_in[1];
    const float* embed_b = (const float*)d_in[2];
    const float* layer_w = (const float*)d_in[3];
    const float* head_w  = (const float*)d_in[4];
    const float* head_b  = (const float*)d_in[5];
    float* out = (float*)d_out;

    uint16_t* ws = (uint16_t*)d_ws;   // 1855 KB of frag-blocks

    const int dynLds = 3 * HALF_BYTES;   // 76800 B -> 2 blocks/CU
    (void)hipFuncSetAttribute((const void*)resmlp_main,
                              hipFuncAttributeMaxDynamicSharedMemorySize, dynLds);

    resmlp_prep<<<(NFRAG_TOTAL + 3) / 4, 256, 0, stream>>>(embed_w, layer_w, head_w, ws);
    resmlp_main<<<512, 256, dynLds, stream>>>(x, embed_b, head_b, ws, out);
}